// Round 1
// baseline (339.492 us; speedup 1.0000x reference)
//
#include <hip/hip_runtime.h>
#include <stdint.h>

#define Bn 32
#define Cc 64
#define Hh 112
#define Ww 112
#define HWp (Hh*Ww)          // 12544
#define NPIX (Bn*HWp)        // 401408
#define ALPHA 0.25f

// workspace layout (bytes)
#define WB1_OFF   0                      // uint64[64*9]
#define WB2_OFF   4608                   // uint64[64*9]
#define SC1_OFF   9216                   // float[64]
#define SC2_OFF   9472                   // float[64]
#define BITS1_OFF 16384                  // uint64[NPIX] = 3,211,264 B
#define BITS2_OFF (16384 + 3211264)      // uint64[NPIX]

// Per-output-channel: scale = mean(|w|) over 576, and 9 tap masks (bit i set if w[o][i][tap] < 0)
__global__ void prep_weights(const float* __restrict__ w, uint64_t* __restrict__ wbits,
                             float* __restrict__ scale) {
    int o = threadIdx.x;  // 64 threads
    uint64_t m[9] = {0,0,0,0,0,0,0,0,0};
    float asum = 0.f;
    const float* wo = w + o * Cc * 9;
    for (int i = 0; i < Cc; ++i) {
        #pragma unroll
        for (int t = 0; t < 9; ++t) {
            float v = wo[i * 9 + t];
            asum += fabsf(v);
            if (v < 0.f) m[t] |= (1ull << i);
        }
    }
    #pragma unroll
    for (int t = 0; t < 9; ++t) wbits[o * 9 + t] = m[t];
    scale[o] = asum * (1.f / 576.f);
}

// bits1[n*HW+hw]: bit c = (x[n,c,h,w] + b11[c] < 0)   (bin_act: >=0 -> +1)
__global__ void pack1(const float* __restrict__ x, const float* __restrict__ b11,
                      uint64_t* __restrict__ bits) {
    int idx = blockIdx.x * 256 + threadIdx.x;
    int n = idx / HWp, hw = idx % HWp;
    const float* xp = x + (size_t)n * Cc * HWp + hw;
    uint64_t m = 0;
    #pragma unroll 8
    for (int c = 0; c < Cc; ++c) {
        float v = xp[(size_t)c * HWp] + b11[c];
        if (v < 0.f) m |= (1ull << c);
    }
    bits[idx] = m;
}

__device__ __forceinline__ void load_neigh(const uint64_t* __restrict__ bp,
                                           int h, int w, uint64_t xm[9], int vm[9],
                                           int& nvalid) {
    nvalid = 0;
    #pragma unroll
    for (int t = 0; t < 9; ++t) {
        int dh = t / 3 - 1, dw = t % 3 - 1;
        int hh = h + dh, ww = w + dw;
        bool ok = (hh >= 0) & (hh < Hh) & (ww >= 0) & (ww < Ww);
        xm[t] = ok ? bp[hh * Ww + ww] : 0ull;
        vm[t] = ok ? -1 : 0;
        nvalid += ok ? 1 : 0;
    }
}

// conv1 + residual(x) + b12 + prelu(a1) + b13 -> out1 (stored in d_out), pack bits2 = (out1 + b21 < 0)
__global__ void conv1_ep(const float* __restrict__ x,
                         const uint64_t* __restrict__ bits1,
                         const uint64_t* __restrict__ wb,
                         const float* __restrict__ sc,
                         const float* __restrict__ b12, const float* __restrict__ a1,
                         const float* __restrict__ b13, const float* __restrict__ b21,
                         float* __restrict__ out1, uint64_t* __restrict__ bits2) {
    int idx = blockIdx.x * 256 + threadIdx.x;
    int n = idx / HWp, hw = idx % HWp;
    int h = hw / Ww, w = hw % Ww;
    uint64_t xm[9]; int vm[9]; int nvalid;
    load_neigh(bits1 + (size_t)n * HWp, h, w, xm, vm, nvalid);

    const float* xp = x + (size_t)n * Cc * HWp + hw;
    float* op = out1 + (size_t)n * Cc * HWp + hw;
    uint64_t m2 = 0;
    for (int o = 0; o < Cc; ++o) {
        int s = 0;
        #pragma unroll
        for (int t = 0; t < 9; ++t)
            s += __builtin_popcountll(xm[t] ^ wb[o * 9 + t]) & vm[t];
        int dot = (nvalid << 6) - (s << 1);
        float conv = sc[o] * (float)dot;
        float v = xp[(size_t)o * HWp] + ALPHA * conv;   // residual is original x
        v += b12[o];
        v = v >= 0.f ? v : a1[o] * v;
        v += b13[o];
        op[(size_t)o * HWp] = v;
        if (v + b21[o] < 0.f) m2 |= (1ull << o);
    }
    bits2[idx] = m2;
}

// conv2 + residual(out1, in-place in io) + b22 + prelu(a2) + b23 -> io
__global__ void conv2_ep(const uint64_t* __restrict__ bits2,
                         const uint64_t* __restrict__ wb,
                         const float* __restrict__ sc,
                         const float* __restrict__ b22, const float* __restrict__ a2,
                         const float* __restrict__ b23,
                         float* __restrict__ io) {
    int idx = blockIdx.x * 256 + threadIdx.x;
    int n = idx / HWp, hw = idx % HWp;
    int h = hw / Ww, w = hw % Ww;
    uint64_t xm[9]; int vm[9]; int nvalid;
    load_neigh(bits2 + (size_t)n * HWp, h, w, xm, vm, nvalid);

    float* iop = io + (size_t)n * Cc * HWp + hw;
    for (int o = 0; o < Cc; ++o) {
        int s = 0;
        #pragma unroll
        for (int t = 0; t < 9; ++t)
            s += __builtin_popcountll(xm[t] ^ wb[o * 9 + t]) & vm[t];
        int dot = (nvalid << 6) - (s << 1);
        float conv = sc[o] * (float)dot;
        float v = ALPHA * conv + iop[(size_t)o * HWp];
        v += b22[o];
        v = v >= 0.f ? v : a2[o] * v;
        v += b23[o];
        iop[(size_t)o * HWp] = v;
    }
}

extern "C" void kernel_launch(void* const* d_in, const int* in_sizes, int n_in,
                              void* d_out, int out_size, void* d_ws, size_t ws_size,
                              hipStream_t stream) {
    const float* x    = (const float*)d_in[0];
    const float* w3   = (const float*)d_in[1];
    const float* wpw  = (const float*)d_in[2];
    const float* b11  = (const float*)d_in[3];
    const float* b12  = (const float*)d_in[4];
    const float* b13  = (const float*)d_in[5];
    const float* b21  = (const float*)d_in[6];
    const float* b22  = (const float*)d_in[7];
    const float* b23  = (const float*)d_in[8];
    const float* a1   = (const float*)d_in[9];
    const float* a2   = (const float*)d_in[10];

    char* ws = (char*)d_ws;
    uint64_t* wb1   = (uint64_t*)(ws + WB1_OFF);
    uint64_t* wb2   = (uint64_t*)(ws + WB2_OFF);
    float*    sc1   = (float*)(ws + SC1_OFF);
    float*    sc2   = (float*)(ws + SC2_OFF);
    uint64_t* bits1 = (uint64_t*)(ws + BITS1_OFF);
    uint64_t* bits2 = (uint64_t*)(ws + BITS2_OFF);
    float*    out   = (float*)d_out;

    const int nblk = NPIX / 256;  // 1568, exact

    prep_weights<<<1, 64, 0, stream>>>(w3,  wb1, sc1);
    prep_weights<<<1, 64, 0, stream>>>(wpw, wb2, sc2);
    pack1<<<nblk, 256, 0, stream>>>(x, b11, bits1);
    conv1_ep<<<nblk, 256, 0, stream>>>(x, bits1, wb1, sc1, b12, a1, b13, b21, out, bits2);
    conv2_ep<<<nblk, 256, 0, stream>>>(bits2, wb2, sc2, b22, a2, b23, out);
}

// Round 2
// 328.746 us; speedup vs baseline: 1.0327x; 1.0327x over previous
//
#include <hip/hip_runtime.h>
#include <stdint.h>

#define Bn 32
#define Cc 64
#define Hh 112
#define Ww 112
#define HWp (Hh*Ww)          // 12544
#define NPIX (Bn*HWp)        // 401408
#define GPR (Ww/4)           // 28 pixel-groups per row
#define GPI (GPR*Hh)         // 3136 groups per image
#define NGRP (Bn*GPI)        // 100352 groups total
#define ALPHA 0.25f

// workspace layout (bytes)
#define WB1_OFF   0                      // uint64[64*9]
#define WB2_OFF   4608                   // uint64[64*9]
#define SC1_OFF   9216                   // float[64]
#define SC2_OFF   9472                   // float[64]
#define BITS1_OFF 16384                  // uint64[NPIX] = 3,211,264 B
#define BITS2_OFF (16384 + 3211264)      // uint64[NPIX]

// 128 blocks x 64 threads. Block b<64: w3 -> wb1/sc1, o=b. Block b>=64: wpw -> wb2/sc2.
// Thread i (lane) owns input channel i; __ballot builds the 64-bit tap mask directly.
__global__ __launch_bounds__(64) void prep_weights(
        const float* __restrict__ w3, const float* __restrict__ wpw,
        uint64_t* __restrict__ wb1, uint64_t* __restrict__ wb2,
        float* __restrict__ sc1, float* __restrict__ sc2) {
    int b = blockIdx.x;
    int lane = threadIdx.x;
    const float* w   = (b < 64) ? w3  : wpw;
    uint64_t* wbits  = (b < 64) ? wb1 : wb2;
    float*    scale  = (b < 64) ? sc1 : sc2;
    int o = b & 63;
    const float* wp = w + ((size_t)o * Cc + lane) * 9;
    float v[9];
    float asum = 0.f;
    #pragma unroll
    for (int t = 0; t < 9; ++t) { v[t] = wp[t]; asum += fabsf(v[t]); }
    uint64_t mym = 0;
    #pragma unroll
    for (int t = 0; t < 9; ++t) {
        uint64_t bal = __ballot(v[t] < 0.f);
        if (lane == t) mym = bal;
    }
    if (lane < 9) wbits[o * 9 + lane] = mym;
    #pragma unroll
    for (int off = 32; off > 0; off >>= 1) asum += __shfl_down(asum, off, 64);
    if (lane == 0) scale[o] = asum * (1.f / 576.f);
}

// 4 pixels/thread: bits1 bit c = (x[n,c,h,w] + b11[c] < 0)
__global__ __launch_bounds__(128) void pack1(const float* __restrict__ x,
                                             const float* __restrict__ b11,
                                             uint64_t* __restrict__ bits) {
    int gid = blockIdx.x * 128 + threadIdx.x;
    int n = gid / (HWp / 4);
    int r = gid - n * (HWp / 4);
    size_t base = (size_t)n * Cc * HWp + (size_t)r * 4;
    uint64_t m0 = 0, m1 = 0, m2 = 0, m3 = 0;
    #pragma unroll 8
    for (int c = 0; c < Cc; ++c) {
        float4 v = *(const float4*)(x + base + (size_t)c * HWp);
        float bc = b11[c];
        uint64_t bit = 1ull << c;
        if (v.x + bc < 0.f) m0 |= bit;
        if (v.y + bc < 0.f) m1 |= bit;
        if (v.z + bc < 0.f) m2 |= bit;
        if (v.w + bc < 0.f) m3 |= bit;
    }
    uint64_t* bp = bits + (size_t)n * HWp + (size_t)r * 4;
    ulonglong2* bp2 = (ulonglong2*)bp;
    bp2[0] = make_ulonglong2(m0, m1);
    bp2[1] = make_ulonglong2(m2, m3);
}

// Load the 3x6 bit window + validity masks for a 4-pixel group at (h, w0..w0+3).
__device__ __forceinline__ void load_window(const uint64_t* __restrict__ bp,
                                            int h, int w0,
                                            uint64_t win[3][6], int vmx[3][6],
                                            int nvalid[4]) {
    int vc0 = (w0 > 0) ? -1 : 0;
    int vc5 = (w0 < Ww - 4) ? -1 : 0;
    #pragma unroll
    for (int dh = 0; dh < 3; ++dh) {
        int hh = h + dh - 1;
        bool okr = (hh >= 0) & (hh < Hh);
        int vr = okr ? -1 : 0;
        const uint64_t* rp = bp + hh * Ww + (w0 - 1);
        #pragma unroll
        for (int c = 0; c < 6; ++c) {
            int vcc = (c == 0) ? vc0 : (c == 5) ? vc5 : -1;
            int m = vr & vcc;
            vmx[dh][c] = m;
            win[dh][c] = (m != 0) ? rp[c] : 0ull;
        }
    }
    #pragma unroll
    for (int p = 0; p < 4; ++p) {
        int nv = 0;
        #pragma unroll
        for (int dh = 0; dh < 3; ++dh)
            #pragma unroll
            for (int dw = 0; dw < 3; ++dw)
                nv += vmx[dh][p + dw] & 1;
        nvalid[p] = nv;
    }
}

// conv1 + residual(x) + b12 + prelu(a1) + b13 -> out1 (in d_out); pack bits2 = (out1+b21 < 0)
__global__ __launch_bounds__(128) void conv1_ep(
        const float* __restrict__ x, const uint64_t* __restrict__ bits1,
        const uint64_t* __restrict__ wb, const float* __restrict__ sc,
        const float* __restrict__ b12, const float* __restrict__ a1,
        const float* __restrict__ b13, const float* __restrict__ b21,
        float* __restrict__ out1, uint64_t* __restrict__ bits2) {
    int gid = blockIdx.x * 128 + threadIdx.x;
    int n = gid / GPI;
    int r = gid - n * GPI;
    int h = r / GPR;
    int w0 = (r - h * GPR) * 4;

    uint64_t win[3][6]; int vmx[3][6]; int nvalid[4];
    load_window(bits1 + (size_t)n * HWp, h, w0, win, vmx, nvalid);

    size_t pbase = (size_t)n * Cc * HWp + h * Ww + w0;
    const float* xp = x + pbase;
    float* op = out1 + pbase;
    uint64_t m2[4] = {0, 0, 0, 0};

    for (int o = 0; o < Cc; ++o) {
        const uint64_t* wbo = wb + o * 9;
        int s0 = 0, s1 = 0, s2 = 0, s3 = 0;
        #pragma unroll
        for (int dh = 0; dh < 3; ++dh) {
            #pragma unroll
            for (int dw = 0; dw < 3; ++dw) {
                uint64_t wv = wbo[dh * 3 + dw];
                s0 += __popcll(win[dh][0 + dw] ^ wv) & vmx[dh][0 + dw];
                s1 += __popcll(win[dh][1 + dw] ^ wv) & vmx[dh][1 + dw];
                s2 += __popcll(win[dh][2 + dw] ^ wv) & vmx[dh][2 + dw];
                s3 += __popcll(win[dh][3 + dw] ^ wv) & vmx[dh][3 + dw];
            }
        }
        float asc = ALPHA * sc[o];
        float4 xv = *(const float4*)(xp + (size_t)o * HWp);
        float v0 = xv.x + asc * (float)((nvalid[0] << 6) - 2 * s0);
        float v1 = xv.y + asc * (float)((nvalid[1] << 6) - 2 * s1);
        float v2 = xv.z + asc * (float)((nvalid[2] << 6) - 2 * s2);
        float v3 = xv.w + asc * (float)((nvalid[3] << 6) - 2 * s3);
        float bb = b12[o], aa = a1[o], cc = b13[o], d21 = b21[o];
        v0 += bb; v0 = v0 >= 0.f ? v0 : aa * v0; v0 += cc;
        v1 += bb; v1 = v1 >= 0.f ? v1 : aa * v1; v1 += cc;
        v2 += bb; v2 = v2 >= 0.f ? v2 : aa * v2; v2 += cc;
        v3 += bb; v3 = v3 >= 0.f ? v3 : aa * v3; v3 += cc;
        *(float4*)(op + (size_t)o * HWp) = make_float4(v0, v1, v2, v3);
        uint64_t bit = 1ull << o;
        if (v0 + d21 < 0.f) m2[0] |= bit;
        if (v1 + d21 < 0.f) m2[1] |= bit;
        if (v2 + d21 < 0.f) m2[2] |= bit;
        if (v3 + d21 < 0.f) m2[3] |= bit;
    }
    ulonglong2* bq = (ulonglong2*)(bits2 + (size_t)n * HWp + h * Ww + w0);
    bq[0] = make_ulonglong2(m2[0], m2[1]);
    bq[1] = make_ulonglong2(m2[2], m2[3]);
}

// conv2 + residual(out1 in-place in io) + b22 + prelu(a2) + b23 -> io
__global__ __launch_bounds__(128) void conv2_ep(
        const uint64_t* __restrict__ bits2,
        const uint64_t* __restrict__ wb, const float* __restrict__ sc,
        const float* __restrict__ b22, const float* __restrict__ a2,
        const float* __restrict__ b23, float* __restrict__ io) {
    int gid = blockIdx.x * 128 + threadIdx.x;
    int n = gid / GPI;
    int r = gid - n * GPI;
    int h = r / GPR;
    int w0 = (r - h * GPR) * 4;

    uint64_t win[3][6]; int vmx[3][6]; int nvalid[4];
    load_window(bits2 + (size_t)n * HWp, h, w0, win, vmx, nvalid);

    float* iop = io + (size_t)n * Cc * HWp + h * Ww + w0;

    for (int o = 0; o < Cc; ++o) {
        const uint64_t* wbo = wb + o * 9;
        int s0 = 0, s1 = 0, s2 = 0, s3 = 0;
        #pragma unroll
        for (int dh = 0; dh < 3; ++dh) {
            #pragma unroll
            for (int dw = 0; dw < 3; ++dw) {
                uint64_t wv = wbo[dh * 3 + dw];
                s0 += __popcll(win[dh][0 + dw] ^ wv) & vmx[dh][0 + dw];
                s1 += __popcll(win[dh][1 + dw] ^ wv) & vmx[dh][1 + dw];
                s2 += __popcll(win[dh][2 + dw] ^ wv) & vmx[dh][2 + dw];
                s3 += __popcll(win[dh][3 + dw] ^ wv) & vmx[dh][3 + dw];
            }
        }
        float asc = ALPHA * sc[o];
        float4 rv = *(const float4*)(iop + (size_t)o * HWp);
        float v0 = rv.x + asc * (float)((nvalid[0] << 6) - 2 * s0);
        float v1 = rv.y + asc * (float)((nvalid[1] << 6) - 2 * s1);
        float v2 = rv.z + asc * (float)((nvalid[2] << 6) - 2 * s2);
        float v3 = rv.w + asc * (float)((nvalid[3] << 6) - 2 * s3);
        float bb = b22[o], aa = a2[o], cc = b23[o];
        v0 += bb; v0 = v0 >= 0.f ? v0 : aa * v0; v0 += cc;
        v1 += bb; v1 = v1 >= 0.f ? v1 : aa * v1; v1 += cc;
        v2 += bb; v2 = v2 >= 0.f ? v2 : aa * v2; v2 += cc;
        v3 += bb; v3 = v3 >= 0.f ? v3 : aa * v3; v3 += cc;
        *(float4*)(iop + (size_t)o * HWp) = make_float4(v0, v1, v2, v3);
    }
}

extern "C" void kernel_launch(void* const* d_in, const int* in_sizes, int n_in,
                              void* d_out, int out_size, void* d_ws, size_t ws_size,
                              hipStream_t stream) {
    const float* x    = (const float*)d_in[0];
    const float* w3   = (const float*)d_in[1];
    const float* wpw  = (const float*)d_in[2];
    const float* b11  = (const float*)d_in[3];
    const float* b12  = (const float*)d_in[4];
    const float* b13  = (const float*)d_in[5];
    const float* b21  = (const float*)d_in[6];
    const float* b22  = (const float*)d_in[7];
    const float* b23  = (const float*)d_in[8];
    const float* a1   = (const float*)d_in[9];
    const float* a2   = (const float*)d_in[10];

    char* ws = (char*)d_ws;
    uint64_t* wb1   = (uint64_t*)(ws + WB1_OFF);
    uint64_t* wb2   = (uint64_t*)(ws + WB2_OFF);
    float*    sc1   = (float*)(ws + SC1_OFF);
    float*    sc2   = (float*)(ws + SC2_OFF);
    uint64_t* bits1 = (uint64_t*)(ws + BITS1_OFF);
    uint64_t* bits2 = (uint64_t*)(ws + BITS2_OFF);
    float*    out   = (float*)d_out;

    prep_weights<<<128, 64, 0, stream>>>(w3, wpw, wb1, wb2, sc1, sc2);
    pack1<<<NGRP / 128, 128, 0, stream>>>(x, b11, bits1);
    conv1_ep<<<NGRP / 128, 128, 0, stream>>>(x, bits1, wb1, sc1, b12, a1, b13, b21, out, bits2);
    conv2_ep<<<NGRP / 128, 128, 0, stream>>>(bits2, wb2, sc2, b22, a2, b23, out);
}

// Round 3
// 296.859 us; speedup vs baseline: 1.1436x; 1.1074x over previous
//
#include <hip/hip_runtime.h>
#include <hip/hip_fp16.h>
#include <stdint.h>

#define Bn 32
#define Cc 64
#define Hh 112
#define Ww 112
#define HWp (Hh*Ww)            // 12544
#define NPIX (Bn*HWp)          // 401408
#define PW 114                 // padded width
#define PHW (PW*PW)            // 12996 padded cells per image
#define ALPHA 0.25f

// workspace layout (bytes)
#define WB1_OFF   0                      // uint64[64*9]
#define WB2_OFF   4608
#define ASC1_OFF  9216                   // float[64]  (= ALPHA * mean|w|)
#define ASC2_OFF  9472
#define CI1_OFF   9728                   // int[64*9]  cint[o*9+type]
#define CI2_OFF   12032
#define BITS1_OFF 16384                  // uint64[Bn*PHW] = 3,326,976 B (padded, halo=0)
#define BITS2_OFF (16384 + 3326976)      // uint64[Bn*PHW]
#define OUT1H_OFF (16384 + 2*3326976)    // __half[NPIX*Cc] = 51,380,224 B (fp16 path)
#define WS_NEED   (OUT1H_OFF + (size_t)NPIX*Cc*2)

// 128 blocks x 64 lanes; block b<64 -> conv1 tables (o=b), else conv2.
// Lane i owns input channel i; __ballot builds each 64-bit tap mask.
// Also emits cint[o][type] = 576 - sum_{invalid taps} (64 - 2*popc(wmask_t)).
__global__ __launch_bounds__(64) void prep_weights(
        const float* __restrict__ w3, const float* __restrict__ wpw,
        uint64_t* __restrict__ wb1, uint64_t* __restrict__ wb2,
        float* __restrict__ asc1, float* __restrict__ asc2,
        int* __restrict__ ci1, int* __restrict__ ci2) {
    int b = blockIdx.x;
    int lane = threadIdx.x;
    const float* w  = (b < 64) ? w3   : wpw;
    uint64_t* wbits = (b < 64) ? wb1  : wb2;
    float*    ascp  = (b < 64) ? asc1 : asc2;
    int*      cip   = (b < 64) ? ci1  : ci2;
    int o = b & 63;
    const float* wp = w + ((size_t)o * Cc + lane) * 9;
    float v[9]; float asum = 0.f;
    #pragma unroll
    for (int t = 0; t < 9; ++t) { v[t] = wp[t]; asum += fabsf(v[t]); }
    uint64_t bal[9];
    #pragma unroll
    for (int t = 0; t < 9; ++t) bal[t] = __ballot(v[t] < 0.f);
    if (lane < 9) {
        wbits[o * 9 + lane] = bal[lane];
        int ty = lane, tr = ty / 3, tc = ty % 3;
        int sum = 0;
        #pragma unroll
        for (int t = 0; t < 9; ++t) {
            int r = t / 3, c = t % 3;
            bool inv = (tr == 0 && r == 0) || (tr == 2 && r == 2) ||
                       (tc == 0 && c == 0) || (tc == 2 && c == 2);
            if (inv) sum += 64 - 2 * (int)__popcll(bal[t]);
        }
        cip[o * 9 + ty] = 576 - sum;
    }
    #pragma unroll
    for (int off = 32; off > 0; off >>= 1) asum += __shfl_down(asum, off, 64);
    if (lane == 0) ascp[o] = ALPHA * asum * (1.f / 576.f);
}

// One thread per PADDED cell. Halo cells: write 0 to bits1 AND bits2 halos.
// Interior: bit c = (x[n,c,h,w] + b11[c] < 0).
__global__ __launch_bounds__(256) void pack1(const float* __restrict__ x,
                                             const float* __restrict__ b11,
                                             uint64_t* __restrict__ bits1,
                                             uint64_t* __restrict__ bits2) {
    int pc = blockIdx.x * 256 + threadIdx.x;
    if (pc >= PHW) return;
    int n = blockIdx.y;
    int ph = pc / PW, pw = pc - ph * PW;
    size_t bi = (size_t)n * PHW + pc;
    if (ph == 0 || ph == PW - 1 || pw == 0 || pw == PW - 1) {
        bits1[bi] = 0; bits2[bi] = 0;
        return;
    }
    int hw = (ph - 1) * Ww + (pw - 1);
    const float* xp = x + (size_t)n * Cc * HWp + hw;
    uint64_t m = 0;
    #pragma unroll 8
    for (int c = 0; c < Cc; ++c) {
        if (xp[(size_t)c * HWp] + b11[c] < 0.f) m |= (1ull << c);
    }
    bits1[bi] = m;
}

// conv1 + residual(x) + b12/prelu(a1)/b13 -> out1 (OutT); pack bits2=(out1+b21<0).
template <typename OutT>
__global__ __launch_bounds__(256) void conv1_ep(
        const float* __restrict__ x, const uint64_t* __restrict__ bits1,
        const uint64_t* __restrict__ wb, const float* __restrict__ asc,
        const int* __restrict__ cint,
        const float* __restrict__ b12, const float* __restrict__ a1,
        const float* __restrict__ b13, const float* __restrict__ b21,
        OutT* __restrict__ out1, uint64_t* __restrict__ bits2) {
    __shared__ int lci[Cc * 12];
    for (int i = threadIdx.x; i < Cc * 9; i += 256) {
        int o = i / 9, ty = i - o * 9;
        lci[o * 12 + ty] = cint[i];
    }
    __syncthreads();

    int hw = blockIdx.x * 256 + threadIdx.x;     // 49*256 = 12544 exact
    int n = blockIdx.y;
    int h = hw / Ww, w = hw - h * Ww;
    int t9 = ((h == 0) ? 0 : (h == Hh - 1) ? 6 : 3) +
             ((w == 0) ? 0 : (w == Ww - 1) ? 2 : 1);

    const uint64_t* bp = bits1 + (size_t)n * PHW + (h + 1) * PW + (w + 1);
    uint64_t w00 = bp[-PW - 1], w01 = bp[-PW], w02 = bp[-PW + 1];
    uint64_t w10 = bp[-1],      w11 = bp[0],   w12 = bp[1];
    uint64_t w20 = bp[PW - 1],  w21 = bp[PW],  w22 = bp[PW + 1];

    const float* xp = x + (size_t)n * Cc * HWp + hw;
    OutT* op = out1 + (size_t)n * Cc * HWp + hw;
    uint64_t m2 = 0;

    for (int o = 0; o < Cc; ++o) {
        const uint64_t* wo = wb + o * 9;
        int s;
        s  = (int)__popcll(w00 ^ wo[0]);
        s += (int)__popcll(w01 ^ wo[1]);
        s += (int)__popcll(w02 ^ wo[2]);
        s += (int)__popcll(w10 ^ wo[3]);
        s += (int)__popcll(w11 ^ wo[4]);
        s += (int)__popcll(w12 ^ wo[5]);
        s += (int)__popcll(w20 ^ wo[6]);
        s += (int)__popcll(w21 ^ wo[7]);
        s += (int)__popcll(w22 ^ wo[8]);
        int m = lci[o * 12 + t9] - (s << 1);
        float v = fmaf(asc[o], (float)m, xp[(size_t)o * HWp]);
        v += b12[o];
        v = v >= 0.f ? v : a1[o] * v;
        v += b13[o];
        op[(size_t)o * HWp] = (OutT)v;
        if (v + b21[o] < 0.f) m2 |= (1ull << o);
    }
    bits2[(size_t)n * PHW + (h + 1) * PW + (w + 1)] = m2;
}

// conv2 + residual(out1) + b22/prelu(a2)/b23 -> out (fp32).
template <typename InT>
__global__ __launch_bounds__(256) void conv2_ep(
        const uint64_t* __restrict__ bits2, const InT* __restrict__ out1,
        const uint64_t* __restrict__ wb, const float* __restrict__ asc,
        const int* __restrict__ cint,
        const float* __restrict__ b22, const float* __restrict__ a2,
        const float* __restrict__ b23, float* __restrict__ out) {
    __shared__ int lci[Cc * 12];
    for (int i = threadIdx.x; i < Cc * 9; i += 256) {
        int o = i / 9, ty = i - o * 9;
        lci[o * 12 + ty] = cint[i];
    }
    __syncthreads();

    int hw = blockIdx.x * 256 + threadIdx.x;
    int n = blockIdx.y;
    int h = hw / Ww, w = hw - h * Ww;
    int t9 = ((h == 0) ? 0 : (h == Hh - 1) ? 6 : 3) +
             ((w == 0) ? 0 : (w == Ww - 1) ? 2 : 1);

    const uint64_t* bp = bits2 + (size_t)n * PHW + (h + 1) * PW + (w + 1);
    uint64_t w00 = bp[-PW - 1], w01 = bp[-PW], w02 = bp[-PW + 1];
    uint64_t w10 = bp[-1],      w11 = bp[0],   w12 = bp[1];
    uint64_t w20 = bp[PW - 1],  w21 = bp[PW],  w22 = bp[PW + 1];

    const InT* ip = out1 + (size_t)n * Cc * HWp + hw;
    float* op = out + (size_t)n * Cc * HWp + hw;

    for (int o = 0; o < Cc; ++o) {
        const uint64_t* wo = wb + o * 9;
        int s;
        s  = (int)__popcll(w00 ^ wo[0]);
        s += (int)__popcll(w01 ^ wo[1]);
        s += (int)__popcll(w02 ^ wo[2]);
        s += (int)__popcll(w10 ^ wo[3]);
        s += (int)__popcll(w11 ^ wo[4]);
        s += (int)__popcll(w12 ^ wo[5]);
        s += (int)__popcll(w20 ^ wo[6]);
        s += (int)__popcll(w21 ^ wo[7]);
        s += (int)__popcll(w22 ^ wo[8]);
        int m = lci[o * 12 + t9] - (s << 1);
        float r = (float)ip[(size_t)o * HWp];
        float v = fmaf(asc[o], (float)m, r);
        v += b22[o];
        v = v >= 0.f ? v : a2[o] * v;
        v += b23[o];
        op[(size_t)o * HWp] = v;
    }
}

extern "C" void kernel_launch(void* const* d_in, const int* in_sizes, int n_in,
                              void* d_out, int out_size, void* d_ws, size_t ws_size,
                              hipStream_t stream) {
    const float* x    = (const float*)d_in[0];
    const float* w3   = (const float*)d_in[1];
    const float* wpw  = (const float*)d_in[2];
    const float* b11  = (const float*)d_in[3];
    const float* b12  = (const float*)d_in[4];
    const float* b13  = (const float*)d_in[5];
    const float* b21  = (const float*)d_in[6];
    const float* b22  = (const float*)d_in[7];
    const float* b23  = (const float*)d_in[8];
    const float* a1   = (const float*)d_in[9];
    const float* a2   = (const float*)d_in[10];

    char* ws = (char*)d_ws;
    uint64_t* wb1   = (uint64_t*)(ws + WB1_OFF);
    uint64_t* wb2   = (uint64_t*)(ws + WB2_OFF);
    float*    asc1  = (float*)(ws + ASC1_OFF);
    float*    asc2  = (float*)(ws + ASC2_OFF);
    int*      ci1   = (int*)(ws + CI1_OFF);
    int*      ci2   = (int*)(ws + CI2_OFF);
    uint64_t* bits1 = (uint64_t*)(ws + BITS1_OFF);
    uint64_t* bits2 = (uint64_t*)(ws + BITS2_OFF);
    float*    out   = (float*)d_out;

    dim3 pgrid((PHW + 255) / 256, Bn);   // 51 x 32
    dim3 cgrid(HWp / 256, Bn);           // 49 x 32

    prep_weights<<<128, 64, 0, stream>>>(w3, wpw, wb1, wb2, asc1, asc2, ci1, ci2);
    pack1<<<pgrid, 256, 0, stream>>>(x, b11, bits1, bits2);

    if (ws_size >= WS_NEED) {
        __half* out1h = (__half*)(ws + OUT1H_OFF);
        conv1_ep<__half><<<cgrid, 256, 0, stream>>>(x, bits1, wb1, asc1, ci1,
                                                    b12, a1, b13, b21, out1h, bits2);
        conv2_ep<__half><<<cgrid, 256, 0, stream>>>(bits2, out1h, wb2, asc2, ci2,
                                                    b22, a2, b23, out);
    } else {
        conv1_ep<float><<<cgrid, 256, 0, stream>>>(x, bits1, wb1, asc1, ci1,
                                                   b12, a1, b13, b21, out, bits2);
        conv2_ep<float><<<cgrid, 256, 0, stream>>>(bits2, out, wb2, asc2, ci2,
                                                   b22, a2, b23, out);
    }
}

// Round 4
// 294.073 us; speedup vs baseline: 1.1544x; 1.0095x over previous
//
#include <hip/hip_runtime.h>
#include <hip/hip_fp16.h>
#include <stdint.h>

#define Bn 32
#define Cc 64
#define Hh 112
#define Ww 112
#define HWp (Hh*Ww)            // 12544
#define NPIX (Bn*HWp)          // 401408
#define PW 114                 // padded width
#define PHW (PW*PW)            // 12996 padded cells per image
#define ALPHA 0.25f

// workspace layout (bytes)
#define WB1_OFF   0                      // uint64[64*9]
#define WB2_OFF   4608
#define ASC1_OFF  9216                   // float[64]  (= ALPHA * mean|w|)
#define ASC2_OFF  9472
#define CI1_OFF   9728                   // int[64*9]  cint[o*9+type]
#define CI2_OFF   12032
#define BITS1_OFF 16384                  // uint64[Bn*PHW] = 3,326,976 B (padded, halo=0)
#define BITS2_OFF (16384 + 3326976)      // uint64[Bn*PHW]
#define OUT1H_OFF (16384 + 2*3326976)    // __half[NPIX*Cc] = 51,380,224 B (fp16 path)
#define WS_NEED   (OUT1H_OFF + (size_t)NPIX*Cc*2)

// 128 blocks x 64 lanes; block b<64 -> conv1 tables (o=b), else conv2.
__global__ __launch_bounds__(64) void prep_weights(
        const float* __restrict__ w3, const float* __restrict__ wpw,
        uint64_t* __restrict__ wb1, uint64_t* __restrict__ wb2,
        float* __restrict__ asc1, float* __restrict__ asc2,
        int* __restrict__ ci1, int* __restrict__ ci2) {
    int b = blockIdx.x;
    int lane = threadIdx.x;
    const float* w  = (b < 64) ? w3   : wpw;
    uint64_t* wbits = (b < 64) ? wb1  : wb2;
    float*    ascp  = (b < 64) ? asc1 : asc2;
    int*      cip   = (b < 64) ? ci1  : ci2;
    int o = b & 63;
    const float* wp = w + ((size_t)o * Cc + lane) * 9;
    float v[9]; float asum = 0.f;
    #pragma unroll
    for (int t = 0; t < 9; ++t) { v[t] = wp[t]; asum += fabsf(v[t]); }
    uint64_t bal[9];
    #pragma unroll
    for (int t = 0; t < 9; ++t) bal[t] = __ballot(v[t] < 0.f);
    if (lane < 9) {
        wbits[o * 9 + lane] = bal[lane];
        int ty = lane, tr = ty / 3, tc = ty % 3;
        int sum = 0;
        #pragma unroll
        for (int t = 0; t < 9; ++t) {
            int r = t / 3, c = t % 3;
            bool inv = (tr == 0 && r == 0) || (tr == 2 && r == 2) ||
                       (tc == 0 && c == 0) || (tc == 2 && c == 2);
            if (inv) sum += 64 - 2 * (int)__popcll(bal[t]);
        }
        cip[o * 9 + ty] = 576 - sum;
    }
    #pragma unroll
    for (int off = 32; off > 0; off >>= 1) asum += __shfl_down(asum, off, 64);
    if (lane == 0) ascp[o] = ALPHA * asum * (1.f / 576.f);
}

// One thread per PADDED cell; halo cells zero bits1+bits2; interior packs signs.
// Channel loop: two 32-deep prefetch batches to keep loads in flight.
__global__ __launch_bounds__(256) void pack1(const float* __restrict__ x,
                                             const float* __restrict__ b11,
                                             uint64_t* __restrict__ bits1,
                                             uint64_t* __restrict__ bits2) {
    int pc = blockIdx.x * 256 + threadIdx.x;
    if (pc >= PHW) return;
    int n = blockIdx.y;
    int ph = pc / PW, pw = pc - ph * PW;
    size_t bi = (size_t)n * PHW + pc;
    if (ph == 0 || ph == PW - 1 || pw == 0 || pw == PW - 1) {
        bits1[bi] = 0; bits2[bi] = 0;
        return;
    }
    int hw = (ph - 1) * Ww + (pw - 1);
    const float* xp = x + (size_t)n * Cc * HWp + hw;
    uint64_t m = 0;
    #pragma unroll 1
    for (int cc = 0; cc < Cc; cc += 16) {
        float v[16];
        #pragma unroll
        for (int j = 0; j < 16; ++j) v[j] = xp[(size_t)(cc + j) * HWp];
        #pragma unroll
        for (int j = 0; j < 16; ++j)
            if (v[j] + b11[cc + j] < 0.f) m |= (1ull << (cc + j));
    }
    bits1[bi] = m;
}

// conv1 + residual(x) + b12/prelu(a1)/b13 -> out1 (OutT); pack bits2=(out1+b21<0).
// o-loop chunked by 8 with prefetch double-buffer for the x reads.
template <typename OutT>
__global__ __launch_bounds__(256) void conv1_ep(
        const float* __restrict__ x, const uint64_t* __restrict__ bits1,
        const uint64_t* __restrict__ wb, const float* __restrict__ asc,
        const int* __restrict__ cint,
        const float* __restrict__ b12, const float* __restrict__ a1,
        const float* __restrict__ b13, const float* __restrict__ b21,
        OutT* __restrict__ out1, uint64_t* __restrict__ bits2) {
    __shared__ int lci[Cc * 12];
    for (int i = threadIdx.x; i < Cc * 9; i += 256) {
        int o = i / 9, ty = i - o * 9;
        lci[o * 12 + ty] = cint[i];
    }
    __syncthreads();

    int hw = blockIdx.x * 256 + threadIdx.x;     // 49*256 = 12544 exact
    int n = blockIdx.y;
    int h = hw / Ww, w = hw - h * Ww;
    int t9 = ((h == 0) ? 0 : (h == Hh - 1) ? 6 : 3) +
             ((w == 0) ? 0 : (w == Ww - 1) ? 2 : 1);

    const uint64_t* bp = bits1 + (size_t)n * PHW + (h + 1) * PW + (w + 1);
    uint64_t w00 = bp[-PW - 1], w01 = bp[-PW], w02 = bp[-PW + 1];
    uint64_t w10 = bp[-1],      w11 = bp[0],   w12 = bp[1];
    uint64_t w20 = bp[PW - 1],  w21 = bp[PW],  w22 = bp[PW + 1];

    const float* xp = x + (size_t)n * Cc * HWp + hw;
    OutT* op = out1 + (size_t)n * Cc * HWp + hw;
    uint64_t m2 = 0;

    float xv[8], xn[8];
    #pragma unroll
    for (int j = 0; j < 8; ++j) xv[j] = xp[(size_t)j * HWp];

    #pragma unroll 1
    for (int oc = 0; oc < Cc; oc += 8) {
        #pragma unroll
        for (int j = 0; j < 8; ++j) xn[j] = xp[(size_t)((oc + 8 + j) & 63) * HWp];
        #pragma unroll
        for (int j = 0; j < 8; ++j) {
            int o = oc + j;
            const uint64_t* wo = wb + o * 9;
            int s;
            s  = (int)__popcll(w00 ^ wo[0]);
            s += (int)__popcll(w01 ^ wo[1]);
            s += (int)__popcll(w02 ^ wo[2]);
            s += (int)__popcll(w10 ^ wo[3]);
            s += (int)__popcll(w11 ^ wo[4]);
            s += (int)__popcll(w12 ^ wo[5]);
            s += (int)__popcll(w20 ^ wo[6]);
            s += (int)__popcll(w21 ^ wo[7]);
            s += (int)__popcll(w22 ^ wo[8]);
            int m = lci[o * 12 + t9] - (s << 1);
            float v = fmaf(asc[o], (float)m, xv[j]);
            v += b12[o];
            v = v >= 0.f ? v : a1[o] * v;
            v += b13[o];
            op[(size_t)o * HWp] = (OutT)v;
            if (v + b21[o] < 0.f) m2 |= (1ull << o);
        }
        #pragma unroll
        for (int j = 0; j < 8; ++j) xv[j] = xn[j];
    }
    bits2[(size_t)n * PHW + (h + 1) * PW + (w + 1)] = m2;
}

// conv2 + residual(out1) + b22/prelu(a2)/b23 -> out (fp32); same prefetch structure.
template <typename InT>
__global__ __launch_bounds__(256) void conv2_ep(
        const uint64_t* __restrict__ bits2, const InT* __restrict__ out1,
        const uint64_t* __restrict__ wb, const float* __restrict__ asc,
        const int* __restrict__ cint,
        const float* __restrict__ b22, const float* __restrict__ a2,
        const float* __restrict__ b23, float* __restrict__ out) {
    __shared__ int lci[Cc * 12];
    for (int i = threadIdx.x; i < Cc * 9; i += 256) {
        int o = i / 9, ty = i - o * 9;
        lci[o * 12 + ty] = cint[i];
    }
    __syncthreads();

    int hw = blockIdx.x * 256 + threadIdx.x;
    int n = blockIdx.y;
    int h = hw / Ww, w = hw - h * Ww;
    int t9 = ((h == 0) ? 0 : (h == Hh - 1) ? 6 : 3) +
             ((w == 0) ? 0 : (w == Ww - 1) ? 2 : 1);

    const uint64_t* bp = bits2 + (size_t)n * PHW + (h + 1) * PW + (w + 1);
    uint64_t w00 = bp[-PW - 1], w01 = bp[-PW], w02 = bp[-PW + 1];
    uint64_t w10 = bp[-1],      w11 = bp[0],   w12 = bp[1];
    uint64_t w20 = bp[PW - 1],  w21 = bp[PW],  w22 = bp[PW + 1];

    const InT* ip = out1 + (size_t)n * Cc * HWp + hw;
    float* op = out + (size_t)n * Cc * HWp + hw;

    InT rv[8], rn[8];
    #pragma unroll
    for (int j = 0; j < 8; ++j) rv[j] = ip[(size_t)j * HWp];

    #pragma unroll 1
    for (int oc = 0; oc < Cc; oc += 8) {
        #pragma unroll
        for (int j = 0; j < 8; ++j) rn[j] = ip[(size_t)((oc + 8 + j) & 63) * HWp];
        #pragma unroll
        for (int j = 0; j < 8; ++j) {
            int o = oc + j;
            const uint64_t* wo = wb + o * 9;
            int s;
            s  = (int)__popcll(w00 ^ wo[0]);
            s += (int)__popcll(w01 ^ wo[1]);
            s += (int)__popcll(w02 ^ wo[2]);
            s += (int)__popcll(w10 ^ wo[3]);
            s += (int)__popcll(w11 ^ wo[4]);
            s += (int)__popcll(w12 ^ wo[5]);
            s += (int)__popcll(w20 ^ wo[6]);
            s += (int)__popcll(w21 ^ wo[7]);
            s += (int)__popcll(w22 ^ wo[8]);
            int m = lci[o * 12 + t9] - (s << 1);
            float v = fmaf(asc[o], (float)m, (float)rv[j]);
            v += b22[o];
            v = v >= 0.f ? v : a2[o] * v;
            v += b23[o];
            op[(size_t)o * HWp] = v;
        }
        #pragma unroll
        for (int j = 0; j < 8; ++j) rv[j] = rn[j];
    }
}

extern "C" void kernel_launch(void* const* d_in, const int* in_sizes, int n_in,
                              void* d_out, int out_size, void* d_ws, size_t ws_size,
                              hipStream_t stream) {
    const float* x    = (const float*)d_in[0];
    const float* w3   = (const float*)d_in[1];
    const float* wpw  = (const float*)d_in[2];
    const float* b11  = (const float*)d_in[3];
    const float* b12  = (const float*)d_in[4];
    const float* b13  = (const float*)d_in[5];
    const float* b21  = (const float*)d_in[6];
    const float* b22  = (const float*)d_in[7];
    const float* b23  = (const float*)d_in[8];
    const float* a1   = (const float*)d_in[9];
    const float* a2   = (const float*)d_in[10];

    char* ws = (char*)d_ws;
    uint64_t* wb1   = (uint64_t*)(ws + WB1_OFF);
    uint64_t* wb2   = (uint64_t*)(ws + WB2_OFF);
    float*    asc1  = (float*)(ws + ASC1_OFF);
    float*    asc2  = (float*)(ws + ASC2_OFF);
    int*      ci1   = (int*)(ws + CI1_OFF);
    int*      ci2   = (int*)(ws + CI2_OFF);
    uint64_t* bits1 = (uint64_t*)(ws + BITS1_OFF);
    uint64_t* bits2 = (uint64_t*)(ws + BITS2_OFF);
    float*    out   = (float*)d_out;

    dim3 pgrid((PHW + 255) / 256, Bn);   // 51 x 32
    dim3 cgrid(HWp / 256, Bn);           // 49 x 32

    prep_weights<<<128, 64, 0, stream>>>(w3, wpw, wb1, wb2, asc1, asc2, ci1, ci2);
    pack1<<<pgrid, 256, 0, stream>>>(x, b11, bits1, bits2);

    if (ws_size >= WS_NEED) {
        __half* out1h = (__half*)(ws + OUT1H_OFF);
        conv1_ep<__half><<<cgrid, 256, 0, stream>>>(x, bits1, wb1, asc1, ci1,
                                                    b12, a1, b13, b21, out1h, bits2);
        conv2_ep<__half><<<cgrid, 256, 0, stream>>>(bits2, out1h, wb2, asc2, ci2,
                                                    b22, a2, b23, out);
    } else {
        conv1_ep<float><<<cgrid, 256, 0, stream>>>(x, bits1, wb1, asc1, ci1,
                                                   b12, a1, b13, b21, out, bits2);
        conv2_ep<float><<<cgrid, 256, 0, stream>>>(bits2, out, wb2, asc2, ci2,
                                                   b22, a2, b23, out);
    }
}